// Round 2
// baseline (376.644 us; speedup 1.0000x reference)
//
#include <hip/hip_runtime.h>
#include <hip/hip_cooperative_groups.h>
#include <math.h>

namespace cg = cooperative_groups;

// Problem constants
#define NB 8
#define NN 225
#define NT 1800          // NB*NN
#define HID 64
#define NE 14400
#define NP 50625         // NN*NN
#define HA 32
#define HC 32
#define BN_EPS 1e-5f

#define NBLK 200
#define NTHR 256
#define GT (NBLK * NTHR)   // 51200 threads

// -------- workspace layout (float offsets) --------
// zeroed in phase 0:
#define WS_AGG0   0         // 1800*2   = 3600
#define WS_AGG1   3600      // 1800*64  = 115200
#define WS_SUM0   118800    // 64
#define WS_SQ0    118864    // 64
#define WS_SUM1   118928    // 64
#define WS_SQ1    118992    // 64
#define WS_ZERO_FLOATS 119056
// fully overwritten before read (no zeroing needed):
#define WS_PM     119056    // 8*25*2 = 400 (per-chunk max,sum)
#define WS_TPRE   119472    // 115200
#define WS_H1     234672    // 115200
#define WS_FEATS  349872    // 115200
#define WS_P1     465072    // 57600
#define WS_P2     522672    // 57600
#define WS_PS     580272    // 256

struct Params {
    const float* x; const int* ei;
    const float* g0_w1; const float* g0_b1; const float* g0_gamma; const float* g0_beta;
    const float* g0_w2; const float* g0_b2;
    const float* g1_w1; const float* g1_b1; const float* g1_gamma; const float* g1_beta;
    const float* g1_w2; const float* g1_b2;
    const float* a_w1; const float* a_b1; const float* a_w2; const float* a_b2;
    const float* c_w1; const float* c_b1; const float* c_w2; const float* c_b2;
    float* ws; float* pi; float* value_out;
};

// Single fused cooperative kernel. 200 blocks x 256 threads (<=1 block/CU needed
// for co-residency on 256 CUs; LDS 37.4 KB/block is well under 160 KB).
__global__ void __launch_bounds__(NTHR) fused_ac(Params P) {
    cg::grid_group grid = cg::this_grid();
    __shared__ float smem[9344];   // 37376 B, aliased per phase

    const int t   = threadIdx.x;
    const int blk = blockIdx.x;
    const int g   = blk * NTHR + t;
    const int c   = t & 63;        // channel lane
    const int rg  = t >> 6;        // row group 0..3

    float* ws    = P.ws;
    float* agg0  = ws + WS_AGG0;
    float* agg1  = ws + WS_AGG1;
    float* sum0  = ws + WS_SUM0;
    float* sq0   = ws + WS_SQ0;
    float* sum1  = ws + WS_SUM1;
    float* sq1   = ws + WS_SQ1;
    float* pm    = ws + WS_PM;
    float* tpre  = ws + WS_TPRE;
    float* h1    = ws + WS_H1;
    float* feats = ws + WS_FEATS;
    float* P1    = ws + WS_P1;
    float* P2    = ws + WS_P2;
    float* Ps    = ws + WS_PS;

    // ---- P0: zero accumulator region (ws is poisoned 0xAA before every call) ----
    for (int i = g; i < WS_ZERO_FLOATS; i += GT) ws[i] = 0.f;
    grid.sync();

    // ---- P1: layer-0 scatter  agg0[dst] += x[src]  (2 channels) ----
    if (g < NE * 2) {
        int e = g >> 1, ch = g & 1;
        int src = P.ei[e], dst = P.ei[NE + e];
        atomicAdd(&agg0[dst * 2 + ch], P.x[src * 2 + ch]);
    }
    grid.sync();

    // ---- P2: layer-0 linear (2->64) + BN stats ----  (block handles 9 rows)
    {
        float* red = smem;                 // 512
        int base = blk * 9;
        float w0 = P.g0_w1[c], w1c = P.g0_w1[64 + c], bc = P.g0_b1[c];
        float ls = 0.f, lq = 0.f;
        for (int rr = rg; rr < 9; rr += 4) {
            int r = base + rr;
            float i0 = P.x[r * 2]     + agg0[r * 2];
            float i1 = P.x[r * 2 + 1] + agg0[r * 2 + 1];
            float v = bc + i0 * w0 + i1 * w1c;
            tpre[r * 64 + c] = v;
            ls += v; lq += v * v;
        }
        red[t] = ls; red[256 + t] = lq;
        __syncthreads();
        if (t < 64) {
            float s = red[t] + red[64 + t] + red[128 + t] + red[192 + t];
            float q = red[256 + t] + red[320 + t] + red[384 + t] + red[448 + t];
            atomicAdd(&sum0[t], s);
            atomicAdd(&sq0[t], q);
        }
        __syncthreads();
    }
    grid.sync();

    // ---- P3: layer-0 BN + ReLU + linear (64->64) -> h1 ----
    {
        float* y   = smem;                 // 9*64 = 576
        float* w2s = smem + 576;           // 4096
        for (int i = t; i < 4096; i += NTHR) w2s[i] = P.g0_w2[i];
        float m = sum0[c] * (1.f / NT);
        float v = sq0[c] * (1.f / NT) - m * m;
        float inv = rsqrtf(v + BN_EPS);
        float ga = P.g0_gamma[c], be = P.g0_beta[c];
        int base = blk * 9;
        for (int rr = rg; rr < 9; rr += 4) {
            int r = base + rr;
            float yv = (tpre[r * 64 + c] - m) * inv * ga + be;
            y[rr * 64 + c] = fmaxf(yv, 0.f);
        }
        __syncthreads();
        float bc = P.g0_b2[c];
        for (int rr = rg; rr < 9; rr += 4) {
            int r = base + rr;
            float acc = bc;
#pragma unroll
            for (int k = 0; k < 64; ++k) acc += y[rr * 64 + k] * w2s[k * 64 + c];
            h1[r * 64 + c] = acc;
        }
        __syncthreads();
    }
    grid.sync();

    // ---- P4: layer-1 scatter  agg1[dst] += h1[src]  (64 ch, float4 loads) ----
    for (int idx = g; idx < NE * 16; idx += GT) {
        int e = idx >> 4, q = idx & 15;
        int src = P.ei[e], dst = P.ei[NE + e];
        const float4 v = ((const float4*)h1)[src * 16 + q];
        float* a = &agg1[dst * 64 + q * 4];
        atomicAdd(a + 0, v.x); atomicAdd(a + 1, v.y);
        atomicAdd(a + 2, v.z); atomicAdd(a + 3, v.w);
    }
    grid.sync();

    // ---- P5: layer-1 linear (64->64) + BN stats ----
    {
        float* in  = smem;                 // 576
        float* red = smem + 576;           // 512
        float* w1s = smem + 1088;          // 4096
        for (int i = t; i < 4096; i += NTHR) w1s[i] = P.g1_w1[i];
        int base = blk * 9;
        for (int rr = rg; rr < 9; rr += 4) {
            int r = base + rr;
            in[rr * 64 + c] = h1[r * 64 + c] + agg1[r * 64 + c];
        }
        __syncthreads();
        float bc = P.g1_b1[c];
        float ls = 0.f, lq = 0.f;
        for (int rr = rg; rr < 9; rr += 4) {
            int r = base + rr;
            float acc = bc;
#pragma unroll
            for (int k = 0; k < 64; ++k) acc += in[rr * 64 + k] * w1s[k * 64 + c];
            tpre[r * 64 + c] = acc;
            ls += acc; lq += acc * acc;
        }
        red[t] = ls; red[256 + t] = lq;
        __syncthreads();
        if (t < 64) {
            float s = red[t] + red[64 + t] + red[128 + t] + red[192 + t];
            float q = red[256 + t] + red[320 + t] + red[384 + t] + red[448 + t];
            atomicAdd(&sum1[t], s);
            atomicAdd(&sq1[t], q);
        }
        __syncthreads();
    }
    grid.sync();

    // ---- P6: layer-1 BN + ReLU + linear (64->64) -> feats, + actor node projections ----
    {
        float* y    = smem;                // 576
        float* f    = smem + 576;          // 576
        float* w2s  = smem + 1152;         // 4096
        float* aw1s = smem + 5248;         // 4096 = a_w1 rows [64,192)
        for (int i = t; i < 4096; i += NTHR) {
            w2s[i]  = P.g1_w2[i];
            aw1s[i] = P.a_w1[64 * HA + i];
        }
        float m = sum1[c] * (1.f / NT);
        float v = sq1[c] * (1.f / NT) - m * m;
        float inv = rsqrtf(v + BN_EPS);
        float ga = P.g1_gamma[c], be = P.g1_beta[c];
        int base = blk * 9;
        for (int rr = rg; rr < 9; rr += 4) {
            int r = base + rr;
            float yv = (tpre[r * 64 + c] - m) * inv * ga + be;
            y[rr * 64 + c] = fmaxf(yv, 0.f);
        }
        __syncthreads();
        float bc = P.g1_b2[c];
        for (int rr = rg; rr < 9; rr += 4) {
            int r = base + rr;
            float acc = bc;
#pragma unroll
            for (int k = 0; k < 64; ++k) acc += y[rr * 64 + k] * w2s[k * 64 + c];
            feats[r * 64 + c] = acc;
            f[rr * 64 + c] = acc;
        }
        __syncthreads();
        // P1 <- a_w1 rows [64,128) (node_j term), P2 <- rows [128,192) (node_i term)
        int j = c & 31;
        const float* wb = (c < 32) ? aw1s : (aw1s + 64 * HA);
        for (int rr = rg; rr < 9; rr += 4) {
            int r = base + rr;
            float p = 0.f;
#pragma unroll
            for (int k = 0; k < 64; ++k) p += f[rr * 64 + k] * wb[k * HA + j];
            if (c < 32) P1[r * HA + j] = p;
            else        P2[r * HA + j] = p;
        }
        __syncthreads();
    }
    grid.sync();

    // ---- P7: graph pooling + critic head + actor state projection (blocks 0..7) ----
    if (blk < NB) {
        float* part = smem;                // 4*64
        float* emb  = smem + 256;          // 64
        float* hv   = smem + 320;          // 32
        int b = blk;
        float s = 0.f;
        for (int n = rg; n < NN; n += 4) s += feats[(b * NN + n) * 64 + c];
        part[rg * 64 + c] = s;
        __syncthreads();
        if (t < 64) emb[t] = (part[t] + part[64 + t] + part[128 + t] + part[192 + t]) * (1.f / NN);
        __syncthreads();
        if (t < 32) {
            float acc = P.a_b1[t];
#pragma unroll
            for (int k = 0; k < 64; ++k) acc += emb[k] * P.a_w1[k * HA + t];
            Ps[b * HA + t] = acc;          // includes actor hidden bias
        } else if (t < 64) {
            int j = t - 32;
            float acc = P.c_b1[j];
#pragma unroll
            for (int k = 0; k < 64; ++k) acc += emb[k] * P.c_w1[k * HC + j];
            hv[j] = fmaxf(acc, 0.f);
        }
        __syncthreads();
        if (t == 0) {
            float acc = P.c_b2[0];
#pragma unroll
            for (int j = 0; j < HC; ++j) acc += hv[j] * P.c_w2[j];
            P.value_out[b] = acc;
        }
        __syncthreads();
    }
    grid.sync();

    // ---- P8: pairwise logits + per-chunk softmax stats (e-values stay in registers) ----
    float evals[8];
    float factor_num;   // this block's chunk max (Mc)
    {
        float* P1s = smem;                 // 225*33 = 7425 (padded, conflict-free)
        float* P2s = smem + 7425;          // 288
        float* Psl = smem + 7713;          // 32
        float* w2l = smem + 7745;          // 32
        float* red = smem + 7777;          // 256
        int b = blk / 25, chunk = blk % 25;
        for (int idx = t; idx < NN * HA; idx += NTHR) {
            int j = idx >> 5, k = idx & 31;
            P1s[j * 33 + k] = P1[(b * NN + j) * HA + k];
        }
        for (int idx = t; idx < 9 * HA; idx += NTHR)
            P2s[idx] = P2[(b * NN + chunk * 9) * HA + idx];
        if (t < 32) { Psl[t] = Ps[b * HA + t]; w2l[t] = P.a_w2[t]; }
        __syncthreads();
        float bias2 = P.a_b2[0];
        float lmax = -1e30f;
        for (int p = t, it = 0; p < 2025; p += NTHR, ++it) {
            int i = p / 225, j = p % 225;
            float acc = bias2;
#pragma unroll
            for (int k = 0; k < HA; ++k) {
                float h = Psl[k] + P1s[j * 33 + k] + P2s[i * HA + k];
                acc += fmaxf(h, 0.f) * w2l[k];
            }
            evals[it] = acc;
            lmax = fmaxf(lmax, acc);
        }
        red[t] = lmax; __syncthreads();
        for (int s = 128; s > 0; s >>= 1) {
            if (t < s) red[t] = fmaxf(red[t], red[t + s]);
            __syncthreads();
        }
        float Mc = red[0];
        __syncthreads();
        float ls = 0.f;
        for (int p = t, it = 0; p < 2025; p += NTHR, ++it) {
            evals[it] = expf(evals[it] - Mc);
            ls += evals[it];
        }
        red[t] = ls; __syncthreads();
        for (int s = 128; s > 0; s >>= 1) {
            if (t < s) red[t] += red[t + s];
            __syncthreads();
        }
        if (t == 0) {
            pm[(b * 25 + chunk) * 2]     = Mc;
            pm[(b * 25 + chunk) * 2 + 1] = red[0];
        }
        factor_num = Mc;
        __syncthreads();
    }
    grid.sync();

    // ---- P9: per-batch combine (redundant per block) + scaled write of pi ----
    {
        int b = blk / 25, chunk = blk % 25;
        float M = -1e30f;
        for (int cc = 0; cc < 25; ++cc) M = fmaxf(M, pm[(b * 25 + cc) * 2]);
        float S = 0.f;
        for (int cc = 0; cc < 25; ++cc)
            S += pm[(b * 25 + cc) * 2 + 1] * expf(pm[(b * 25 + cc) * 2] - M);
        float factor = expf(factor_num - M) / S;
        float* outp = P.pi + b * NP + chunk * 2025;
        for (int p = t, it = 0; p < 2025; p += NTHR, ++it)
            outp[p] = evals[it] * factor;
    }
}

extern "C" void kernel_launch(void* const* d_in, const int* in_sizes, int n_in,
                              void* d_out, int out_size, void* d_ws, size_t ws_size,
                              hipStream_t stream) {
    Params P;
    P.x        = (const float*)d_in[0];
    P.ei       = (const int*)d_in[1];
    // d_in[2] = batch_ids (unused: graphs are contiguous 225-node blocks)
    P.g0_w1    = (const float*)d_in[3];
    P.g0_b1    = (const float*)d_in[4];
    P.g0_gamma = (const float*)d_in[5];
    P.g0_beta  = (const float*)d_in[6];
    P.g0_w2    = (const float*)d_in[7];
    P.g0_b2    = (const float*)d_in[8];
    P.g1_w1    = (const float*)d_in[9];
    P.g1_b1    = (const float*)d_in[10];
    P.g1_gamma = (const float*)d_in[11];
    P.g1_beta  = (const float*)d_in[12];
    P.g1_w2    = (const float*)d_in[13];
    P.g1_b2    = (const float*)d_in[14];
    P.a_w1     = (const float*)d_in[15];
    P.a_b1     = (const float*)d_in[16];
    P.a_w2     = (const float*)d_in[17];
    P.a_b2     = (const float*)d_in[18];
    P.c_w1     = (const float*)d_in[19];
    P.c_b1     = (const float*)d_in[20];
    P.c_w2     = (const float*)d_in[21];
    P.c_b2     = (const float*)d_in[22];
    P.ws       = (float*)d_ws;
    P.pi        = (float*)d_out;            // [8, 50625]
    P.value_out = (float*)d_out + NB * NP;  // [8]

    void* args[] = { &P };
    hipLaunchCooperativeKernel((void*)fused_ac, dim3(NBLK), dim3(NTHR), args, 0, stream);
}

// Round 3
// 193.590 us; speedup vs baseline: 1.9456x; 1.9456x over previous
//
#include <hip/hip_runtime.h>
#include <math.h>

// Problem constants
#define NB 8
#define NN 225
#define NT 1800          // NB*NN
#define NE 14400
#define NP 50625         // NN*NN
#define HA 32
#define HC 32
#define BN_EPS 1e-5f

#define RPB 9            // rows per block (200*9 = 1800)
#define NBLK 200
#define NTHR 256
#define LCAP 384         // edge-hit list capacity (mean 72, 6-sigma ~123)

// -------- workspace layout (float offsets); nothing needs pre-zeroing --------
#define WS_TPRE 0        // 1800*64 = 115200 (BN pre-activations, reused layer0/1)
#define WS_H1   115200   // 1800*64
#define WS_P1   230400   // 1800*32
#define WS_P2   288000   // 1800*32
#define WS_PS0  345600   // 200*64 per-block BN sum partials (layer 0)
#define WS_PQ0  358400   // 200*64 sq partials
#define WS_PS1  371200
#define WS_PQ1  384000
#define WS_PEMB 396800   // 200*64 pooling partials
#define WS_SP   409600   // 200 softmax-denominator partials
#define WS_EV   409856   // 405000 exp(logit) values

// ---- stage 1: GIN0 aggregate (gather) + linear 2->64 + BN stat partials ----
__global__ void __launch_bounds__(NTHR) k_lin0g(const float* __restrict__ x,
                                                const int* __restrict__ ei,
                                                const float* __restrict__ w1,
                                                const float* __restrict__ b1,
                                                float* __restrict__ tpre,
                                                float* __restrict__ p0s,
                                                float* __restrict__ p0q) {
    __shared__ float agg[RPB * 2];
    __shared__ int   list[LCAP];
    __shared__ int   cnt;
    __shared__ float red[512];
    const int t = threadIdx.x, base = blockIdx.x * RPB;
    if (t == 0) cnt = 0;
    if (t < RPB * 2) agg[t] = x[(base + (t >> 1)) * 2 + (t & 1)];
    __syncthreads();
    // scan all edges for dst in [base, base+RPB)
    for (int e = t; e < NE; e += NTHR) {
        int dst = ei[NE + e];
        unsigned d = (unsigned)(dst - base);
        if (d < RPB) { int idx = atomicAdd(&cnt, 1); list[idx] = (int)((d << 16) | (unsigned)ei[e]); }
    }
    __syncthreads();
    int tot = cnt * 2;
    for (int idx = t; idx < tot; idx += NTHR) {
        int pk = list[idx >> 1];
        int rr = pk >> 16, src = pk & 0xFFFF, ch = idx & 1;
        atomicAdd(&agg[rr * 2 + ch], x[src * 2 + ch]);
    }
    __syncthreads();
    const int c = t & 63, rg = t >> 6;
    float w0 = w1[c], w1c = w1[64 + c], bc = b1[c];
    float ls = 0.f, lq = 0.f;
    for (int rr = rg; rr < RPB; rr += 4) {
        float v = bc + agg[rr * 2] * w0 + agg[rr * 2 + 1] * w1c;
        tpre[(base + rr) * 64 + c] = v;
        ls += v; lq += v * v;
    }
    red[t] = ls; red[256 + t] = lq;
    __syncthreads();
    if (t < 64) {
        p0s[blockIdx.x * 64 + t] = red[t] + red[64 + t] + red[128 + t] + red[192 + t];
        p0q[blockIdx.x * 64 + t] = red[256 + t] + red[320 + t] + red[384 + t] + red[448 + t];
    }
}

// ---- stage 2: BN0 + ReLU + linear 64->64 -> h1 ----
__global__ void __launch_bounds__(NTHR) k_bnlin0(const float* __restrict__ tpre,
                                                 const float* __restrict__ p0s,
                                                 const float* __restrict__ p0q,
                                                 const float* __restrict__ gamma,
                                                 const float* __restrict__ beta,
                                                 const float* __restrict__ w2,
                                                 const float* __restrict__ b2,
                                                 float* __restrict__ h1) {
    __shared__ float y[RPB * 64];
    __shared__ float w2s[4096];
    __shared__ float red[512];
    __shared__ float mi[128];
    const int t = threadIdx.x, base = blockIdx.x * RPB;
    const int c = t & 63, rg = t >> 6;
    for (int i = t; i < 4096; i += NTHR) w2s[i] = w2[i];
    float ls = 0.f, lq = 0.f;
    for (int p = rg; p < NBLK; p += 4) { ls += p0s[p * 64 + c]; lq += p0q[p * 64 + c]; }
    red[t] = ls; red[256 + t] = lq;
    __syncthreads();
    if (t < 64) {
        float S = red[t] + red[64 + t] + red[128 + t] + red[192 + t];
        float Q = red[256 + t] + red[320 + t] + red[384 + t] + red[448 + t];
        float m = S * (1.f / NT);
        mi[t] = m;
        mi[64 + t] = rsqrtf(Q * (1.f / NT) - m * m + BN_EPS);
    }
    __syncthreads();
    float m = mi[c], inv = mi[64 + c], ga = gamma[c], be = beta[c];
    for (int rr = rg; rr < RPB; rr += 4) {
        float yv = (tpre[(base + rr) * 64 + c] - m) * inv * ga + be;
        y[rr * 64 + c] = fmaxf(yv, 0.f);
    }
    __syncthreads();
    float bc = b2[c];
    for (int rr = rg; rr < RPB; rr += 4) {
        float acc = bc;
#pragma unroll
        for (int k = 0; k < 64; ++k) acc += y[rr * 64 + k] * w2s[k * 64 + c];
        h1[(base + rr) * 64 + c] = acc;
    }
}

// ---- stage 3: GIN1 aggregate (gather, 64ch) + linear 64->64 + BN stat partials ----
__global__ void __launch_bounds__(NTHR) k_lin1g(const float* __restrict__ h1,
                                                const int* __restrict__ ei,
                                                const float* __restrict__ w1,
                                                const float* __restrict__ b1,
                                                float* __restrict__ tpre,
                                                float* __restrict__ p1s,
                                                float* __restrict__ p1q) {
    __shared__ float agg[RPB * 64];
    __shared__ float w1s[4096];
    __shared__ int   list[LCAP];
    __shared__ int   cnt;
    __shared__ float red[512];
    const int t = threadIdx.x, base = blockIdx.x * RPB;
    if (t == 0) cnt = 0;
    for (int i = t; i < RPB * 64; i += NTHR) agg[i] = h1[base * 64 + i];
    for (int i = t; i < 4096; i += NTHR) w1s[i] = w1[i];
    __syncthreads();
    for (int e = t; e < NE; e += NTHR) {
        int dst = ei[NE + e];
        unsigned d = (unsigned)(dst - base);
        if (d < RPB) { int idx = atomicAdd(&cnt, 1); list[idx] = (int)((d << 16) | (unsigned)ei[e]); }
    }
    __syncthreads();
    const int c = t & 63, wid = t >> 6;
    for (int e = wid; e < cnt; e += 4) {
        int pk = list[e];
        int rr = pk >> 16, src = pk & 0xFFFF;
        atomicAdd(&agg[rr * 64 + c], h1[src * 64 + c]);
    }
    __syncthreads();
    const int rg = wid;
    float bc = b1[c];
    float ls = 0.f, lq = 0.f;
    for (int rr = rg; rr < RPB; rr += 4) {
        float acc = bc;
#pragma unroll
        for (int k = 0; k < 64; ++k) acc += agg[rr * 64 + k] * w1s[k * 64 + c];
        tpre[(base + rr) * 64 + c] = acc;
        ls += acc; lq += acc * acc;
    }
    red[t] = ls; red[256 + t] = lq;
    __syncthreads();
    if (t < 64) {
        p1s[blockIdx.x * 64 + t] = red[t] + red[64 + t] + red[128 + t] + red[192 + t];
        p1q[blockIdx.x * 64 + t] = red[256 + t] + red[320 + t] + red[384 + t] + red[448 + t];
    }
}

// ---- stage 4: BN1 + ReLU + linear 64->64 -> feats (regs) + P1/P2 projections + emb partials ----
__global__ void __launch_bounds__(NTHR) k_bnlin1proj(const float* __restrict__ tpre,
                                                     const float* __restrict__ p1s,
                                                     const float* __restrict__ p1q,
                                                     const float* __restrict__ gamma,
                                                     const float* __restrict__ beta,
                                                     const float* __restrict__ w2,
                                                     const float* __restrict__ b2,
                                                     const float* __restrict__ a_w1,
                                                     float* __restrict__ P1,
                                                     float* __restrict__ P2,
                                                     float* __restrict__ pemb) {
    __shared__ float y[RPB * 64];
    __shared__ float f[RPB * 64];
    __shared__ float w2s[4096];
    __shared__ float aw1s[4096];
    __shared__ float red[512];
    __shared__ float mi[128];
    const int t = threadIdx.x, base = blockIdx.x * RPB;
    const int c = t & 63, rg = t >> 6;
    for (int i = t; i < 4096; i += NTHR) { w2s[i] = w2[i]; aw1s[i] = a_w1[64 * HA + i]; }
    float ls = 0.f, lq = 0.f;
    for (int p = rg; p < NBLK; p += 4) { ls += p1s[p * 64 + c]; lq += p1q[p * 64 + c]; }
    red[t] = ls; red[256 + t] = lq;
    __syncthreads();
    if (t < 64) {
        float S = red[t] + red[64 + t] + red[128 + t] + red[192 + t];
        float Q = red[256 + t] + red[320 + t] + red[384 + t] + red[448 + t];
        float m = S * (1.f / NT);
        mi[t] = m;
        mi[64 + t] = rsqrtf(Q * (1.f / NT) - m * m + BN_EPS);
    }
    __syncthreads();
    float m = mi[c], inv = mi[64 + c], ga = gamma[c], be = beta[c];
    for (int rr = rg; rr < RPB; rr += 4) {
        float yv = (tpre[(base + rr) * 64 + c] - m) * inv * ga + be;
        y[rr * 64 + c] = fmaxf(yv, 0.f);
    }
    __syncthreads();
    float bc = b2[c];
    for (int rr = rg; rr < RPB; rr += 4) {
        float acc = bc;
#pragma unroll
        for (int k = 0; k < 64; ++k) acc += y[rr * 64 + k] * w2s[k * 64 + c];
        f[rr * 64 + c] = acc;
    }
    __syncthreads();
    if (t < 64) {    // pooling partial for this block's 9 rows (all same batch: 225 = 25*9)
        float pe = 0.f;
#pragma unroll
        for (int rr = 0; rr < RPB; ++rr) pe += f[rr * 64 + t];
        pemb[blockIdx.x * 64 + t] = pe;
    }
    // P1 <- a_w1 rows [64,128) (node_j term), P2 <- rows [128,192) (node_i term)
    int j = c & 31;
    const float* wb = (c < 32) ? aw1s : (aw1s + 64 * HA);
    for (int rr = rg; rr < RPB; rr += 4) {
        float p = 0.f;
#pragma unroll
        for (int k = 0; k < 64; ++k) p += f[rr * 64 + k] * wb[k * HA + j];
        if (c < 32) P1[(base + rr) * HA + j] = p;
        else        P2[(base + rr) * HA + j] = p;
    }
}

// ---- stage 5: pooled emb + Ps (redundant/block) + critic + pairwise exp(logits) + S partials ----
__global__ void __launch_bounds__(NTHR) k_pairs(const float* __restrict__ P1,
                                                const float* __restrict__ P2,
                                                const float* __restrict__ pemb,
                                                const float* __restrict__ a_w1,
                                                const float* __restrict__ a_b1,
                                                const float* __restrict__ a_w2,
                                                const float* __restrict__ a_b2,
                                                const float* __restrict__ c_w1,
                                                const float* __restrict__ c_b1,
                                                const float* __restrict__ c_w2,
                                                const float* __restrict__ c_b2,
                                                float* __restrict__ evbuf,
                                                float* __restrict__ Spart,
                                                float* __restrict__ value_out) {
    __shared__ float Q1[NN * 36];    // Ps+P1, stride 36 (16B-aligned, dense-b128 bank pattern)
    __shared__ float P2s[RPB * HA];
    __shared__ float emb[64];
    __shared__ float Psl[32];
    __shared__ float w2l[32];
    __shared__ float hv[32];
    __shared__ float red[256];
    const int t = threadIdx.x;
    const int b = blockIdx.x / 25, chunk = blockIdx.x % 25;
    if (t < 64) {
        float s = 0.f;
#pragma unroll
        for (int q = 0; q < 25; ++q) s += pemb[(b * 25 + q) * 64 + t];
        emb[t] = s * (1.f / NN);
    }
    __syncthreads();
    if (t < 32) {
        float a = a_b1[t];
#pragma unroll
        for (int m = 0; m < 64; ++m) a += emb[m] * a_w1[m * HA + t];
        Psl[t] = a;
        w2l[t] = a_w2[t];
    } else if (t < 64 && chunk == 0) {
        int j = t - 32;
        float a = c_b1[j];
#pragma unroll
        for (int m = 0; m < 64; ++m) a += emb[m] * c_w1[m * HC + j];
        hv[j] = fmaxf(a, 0.f);
    }
    __syncthreads();
    if (chunk == 0 && t == 0) {
        float a = c_b2[0];
#pragma unroll
        for (int j = 0; j < HC; ++j) a += hv[j] * c_w2[j];
        value_out[b] = a;
    }
    for (int idx = t; idx < NN * HA; idx += NTHR) {
        int j = idx >> 5, k = idx & 31;
        Q1[j * 36 + k] = Psl[k] + P1[(b * NN + j) * HA + k];
    }
    for (int idx = t; idx < RPB * HA; idx += NTHR)
        P2s[idx] = P2[(b * NN + chunk * RPB) * HA + idx];
    __syncthreads();
    const float bias2 = a_b2[0];
    float ls = 0.f;
    float* outp = evbuf + b * NP + chunk * 2025;
    for (int p = t; p < 2025; p += NTHR) {
        int i = p / 225, j = p - i * 225;
        const float4* q4 = (const float4*)&Q1[j * 36];
        const float4* p4 = (const float4*)&P2s[i * HA];
        const float4* w4 = (const float4*)w2l;
        float acc = bias2;
#pragma unroll
        for (int k4 = 0; k4 < 8; ++k4) {
            float4 q = q4[k4], pp = p4[k4], w = w4[k4];
            acc += fmaxf(q.x + pp.x, 0.f) * w.x;
            acc += fmaxf(q.y + pp.y, 0.f) * w.y;
            acc += fmaxf(q.z + pp.z, 0.f) * w.z;
            acc += fmaxf(q.w + pp.w, 0.f) * w.w;
        }
        float ev = expf(acc);   // no max-subtraction: logits O(1), fp32-safe; pi identical
        outp[p] = ev;
        ls += ev;
    }
    red[t] = ls;
    __syncthreads();
    for (int s = 128; s > 0; s >>= 1) {
        if (t < s) red[t] += red[t + s];
        __syncthreads();
    }
    if (t == 0) Spart[blockIdx.x] = red[0];
}

// ---- stage 6: normalize -> pi ----
__global__ void __launch_bounds__(NTHR) k_finish(const float* __restrict__ evbuf,
                                                 const float* __restrict__ Spart,
                                                 float* __restrict__ pi) {
    __shared__ float sp[NBLK];
    __shared__ float sbinv[NB];
    const int t = threadIdx.x;
    if (t < NBLK) sp[t] = Spart[t];
    __syncthreads();
    if (t < NB) {
        float S = 0.f;
#pragma unroll
        for (int q = 0; q < 25; ++q) S += sp[t * 25 + q];
        sbinv[t] = 1.f / S;
    }
    __syncthreads();
    int g = blockIdx.x * NTHR + t;
    if (g < NB * NP) {
        int b = g / NP;
        pi[g] = evbuf[g] * sbinv[b];
    }
}

extern "C" void kernel_launch(void* const* d_in, const int* in_sizes, int n_in,
                              void* d_out, int out_size, void* d_ws, size_t ws_size,
                              hipStream_t stream) {
    const float* x        = (const float*)d_in[0];
    const int*   ei       = (const int*)d_in[1];
    // d_in[2] = batch_ids (unused: graphs are contiguous 225-node blocks)
    const float* g0_w1    = (const float*)d_in[3];
    const float* g0_b1    = (const float*)d_in[4];
    const float* g0_gamma = (const float*)d_in[5];
    const float* g0_beta  = (const float*)d_in[6];
    const float* g0_w2    = (const float*)d_in[7];
    const float* g0_b2    = (const float*)d_in[8];
    const float* g1_w1    = (const float*)d_in[9];
    const float* g1_b1    = (const float*)d_in[10];
    const float* g1_gamma = (const float*)d_in[11];
    const float* g1_beta  = (const float*)d_in[12];
    const float* g1_w2    = (const float*)d_in[13];
    const float* g1_b2    = (const float*)d_in[14];
    const float* a_w1     = (const float*)d_in[15];
    const float* a_b1     = (const float*)d_in[16];
    const float* a_w2     = (const float*)d_in[17];
    const float* a_b2     = (const float*)d_in[18];
    const float* c_w1     = (const float*)d_in[19];
    const float* c_b1     = (const float*)d_in[20];
    const float* c_w2     = (const float*)d_in[21];
    const float* c_b2     = (const float*)d_in[22];

    float* ws   = (float*)d_ws;
    float* tpre = ws + WS_TPRE;
    float* h1   = ws + WS_H1;
    float* P1   = ws + WS_P1;
    float* P2   = ws + WS_P2;
    float* p0s  = ws + WS_PS0;
    float* p0q  = ws + WS_PQ0;
    float* p1s  = ws + WS_PS1;
    float* p1q  = ws + WS_PQ1;
    float* pemb = ws + WS_PEMB;
    float* Sp   = ws + WS_SP;
    float* ev   = ws + WS_EV;

    float* pi        = (float*)d_out;            // [8, 50625]
    float* value_out = (float*)d_out + NB * NP;  // [8]

    k_lin0g<<<NBLK, NTHR, 0, stream>>>(x, ei, g0_w1, g0_b1, tpre, p0s, p0q);
    k_bnlin0<<<NBLK, NTHR, 0, stream>>>(tpre, p0s, p0q, g0_gamma, g0_beta, g0_w2, g0_b2, h1);
    k_lin1g<<<NBLK, NTHR, 0, stream>>>(h1, ei, g1_w1, g1_b1, tpre, p1s, p1q);
    k_bnlin1proj<<<NBLK, NTHR, 0, stream>>>(tpre, p1s, p1q, g1_gamma, g1_beta, g1_w2, g1_b2,
                                            a_w1, P1, P2, pemb);
    k_pairs<<<NBLK, NTHR, 0, stream>>>(P1, P2, pemb, a_w1, a_b1, a_w2, a_b2,
                                       c_w1, c_b1, c_w2, c_b2, ev, Sp, value_out);
    k_finish<<<(NB * NP + NTHR - 1) / NTHR, NTHR, 0, stream>>>(ev, Sp, pi);
}